// Round 3
// baseline (650.808 us; speedup 1.0000x reference)
//
#include <hip/hip_runtime.h>
#include <cstdio>
#include <cstdint>

// Bahdanau attention, N=64, L=1024, H=1024.
//   d = dec_h @ W_dec + b_dec
//   e = enc @ W_enc  (65536x1024x1024 bf16 MFMA GEMM, fused epilogue)
//   scores = tanh(d+e+b_enc) . W_one ; alpha = softmax(scores) (b_one drops)
//   ctx = alpha @ enc ; h_att = ctx @ W_att + b_att
//
// 5 launches: prep (pack_b + pack_a), dterm, score_gemm, ctx_fused, hatt.
//
// Packed layout (16B chunks): chunk index = ((T*16 + kt)*8 + c)*128 + m
//   T = row>>7, m = row&127, kt = col>>6, c = (col&63)>>3.
//
// score_gemm R3 schedule: 32 K-slices of 32-k. LDS: 4 slots x (A16K+B16K).
// ONE merged phase per slice:
//   RDS (12 ds_read_b128: af[8], bg[4]) ; stage slice g+3 (4 gl_lds)
//   lgkmcnt(0); sched_barrier; setprio(1); 32 MFMA; setprio(0); vmcnt(8); BAR
// Hazards: (W-A-R) stage(g+3) -> slot (g-1)&3; all waves' reads of that slot
// drained at their lgkm0 BEFORE the slice-(g-1) exit barrier, and the stage
// is issued after that barrier. (R-A-W) vmcnt(8) at end of slice g retires
// slice g+1's 4 loads (12 outstanding -> 8); the barrier makes it collective.
// One barrier + one vmcnt per slice (was 2+1 per half-slice): phase overhead
// halved, 32-MFMA cluster per sync, cross-wave ds_read/MFMA overlap enabled.

typedef __bf16 bf16x8 __attribute__((ext_vector_type(8)));
typedef float f32x4 __attribute__((ext_vector_type(4)));
typedef unsigned short us8 __attribute__((ext_vector_type(8)));

static __device__ __forceinline__ unsigned short f2b(float f) {
  union { float f; unsigned u; } v; v.f = f;
  unsigned r = (v.u + 0x7fffu + ((v.u >> 16) & 1u)) >> 16;  // RNE
  return (unsigned short)r;
}
static __device__ __forceinline__ float b2f(unsigned short u) {
  union { unsigned u; float f; } v; v.u = ((unsigned)u) << 16;
  return v.f;
}
static __device__ __forceinline__ void gl_lds16(const void* g, void* l) {
  __builtin_amdgcn_global_load_lds(
      (const __attribute__((address_space(1))) unsigned int*)g,
      (__attribute__((address_space(3))) unsigned int*)l, 16, 0, 0);
}
// branch-free tanh: (u-1)/(u+1), u = 2^(2*log2e*|x|); err ~1e-7
static __device__ __forceinline__ float fast_tanh(float x) {
  float ax = __builtin_fminf(__builtin_fabsf(x), 18.0f);
  float u = __builtin_amdgcn_exp2f(ax * 2.88539008177792681f);
  float t = (u - 1.0f) * __builtin_amdgcn_rcpf(u + 1.0f);
  return __builtin_copysignf(t, x);
}

// ---- prep: blocks [0,128) pack_b, [128, 8320) pack_a ----
// XOR-swizzled LDS tile: chunk (row m, chunk c) -> slot m*8 + (c ^ (m&7)).
__global__ __launch_bounds__(256) void prep_k(
    const float* __restrict__ enc, unsigned short* __restrict__ Ap,
    const float* __restrict__ W_enc, unsigned short* __restrict__ Bp) {
  __shared__ __align__(16) unsigned short tile[8192];  // 16 KB
  const int bid = blockIdx.x;
  const int t = threadIdx.x;

  if (bid < 128) {
    // ---- pack_b: W_enc f32 [k][n] -> Bp bf16 tiled (transposed) ----
    const int Tn = bid >> 4, kt = bid & 15;
    #pragma unroll
    for (int it = 0; it < 8; ++it) {
      int idx = it * 256 + t;
      int kk = idx >> 5, n4 = idx & 31;  // 64 k-rows x 32 float4
      const float4 v = *(const float4*)(W_enc + (size_t)(kt * 64 + kk) * 1024 + Tn * 128 + n4 * 4);
      int c = kk >> 3, j = kk & 7;
      #pragma unroll
      for (int x = 0; x < 4; ++x) {
        int mm = n4 * 4 + x;
        float fv = (x == 0) ? v.x : (x == 1) ? v.y : (x == 2) ? v.z : v.w;
        tile[(mm * 8 + (c ^ (mm & 7))) * 8 + j] = f2b(fv);
      }
    }
    __syncthreads();
    #pragma unroll
    for (int it = 0; it < 4; ++it) {
      int p = it * 256 + t;
      int c = p >> 7, m = p & 127;
      us8 v = *(const us8*)&tile[(m * 8 + (c ^ (m & 7))) * 8];
      *(us8*)(Bp + ((size_t)bid * 1024 + p) * 8) = v;
    }
  } else {
    // ---- pack_a: enc f32 [65536][1024] -> Ap bf16 tiled ----
    const int ba = bid - 128;            // 8192 = T(512) x kt(16)
    const int T = ba >> 4, kt = ba & 15;
    #pragma unroll
    for (int it = 0; it < 8; ++it) {
      int idx = it * 256 + t;
      int m = idx >> 4, c4 = idx & 15;   // 128 rows x 16 float4
      const float4 v = *(const float4*)(enc + (size_t)(T * 128 + m) * 1024 + kt * 64 + c4 * 4);
      ushort4 o;
      o.x = f2b(v.x); o.y = f2b(v.y); o.z = f2b(v.z); o.w = f2b(v.w);
      int c = c4 >> 1, half = c4 & 1;
      *(ushort4*)&tile[(m * 8 + (c ^ (m & 7))) * 8 + half * 4] = o;
    }
    __syncthreads();
    #pragma unroll
    for (int it = 0; it < 4; ++it) {
      int p = it * 256 + t;              // out chunk pos = c*128 + m
      int c = p >> 7, m = p & 127;
      us8 v = *(const us8*)&tile[(m * 8 + (c ^ (m & 7))) * 8];
      *(us8*)(Ap + ((size_t)ba * 1024 + p) * 8) = v;
    }
  }
}

// ---- dterm: addterm[n][j] = dec_h[n] . W_dec[:,j] + b_dec[j] + b_enc[j] ----
__global__ __launch_bounds__(256) void dterm_k(
    const float* __restrict__ dec_h, const float* __restrict__ W_dec,
    const float* __restrict__ b_dec, const float* __restrict__ b_enc,
    float* __restrict__ addterm) {
  __shared__ float xs[1024];
  const int bid2 = blockIdx.x;
  const int jb = bid2 & 3, n = bid2 >> 2;
  const int t = threadIdx.x;
  for (int i = t; i < 1024; i += 256) xs[i] = dec_h[n * 1024 + i];
  __syncthreads();
  int j = jb * 256 + t;
  float s = 0.f;
  #pragma unroll 8
  for (int k = 0; k < 1024; ++k) s += xs[k] * W_dec[(size_t)k * 1024 + j];
  addterm[n * 1024 + j] = s + b_dec[j] + b_enc[j];
}

// ---- fused e-GEMM + tanh + dot(W_one): spart[row][16] partial scores ----
// 256x256 tile, 32 K-slices, 8 waves (wm in {0,1}, wn in {0..3}).
// Per wave: 128x64 output = acc[8][4] of 16x16 frags.
__global__ __launch_bounds__(512, 2) void score_gemm(
    const unsigned short* __restrict__ Ap, const unsigned short* __restrict__ Bp,
    const float* __restrict__ addterm, const float* __restrict__ Wone,
    float* __restrict__ spart) {
  __shared__ __align__(16) unsigned short lA[32768];  // 64 KB: 4 slots x 1024 chunks
  __shared__ __align__(16) unsigned short lB[32768];  // 64 KB
  const int tid = threadIdx.x;
  const int lane = tid & 63, wave = tid >> 6;
  const int wm = wave >> 2, wn = wave & 3;
  const int q = lane >> 4, r = lane & 15;

  // XCD-aware remap: 1024 blocks, xcd = flat&7 gets contiguous tile range;
  // nb fastest so the 4 nb-siblings of one A-slab are L2-adjacent.
  const int flat = blockIdx.x;
  const int tl = (flat & 7) * 128 + (flat >> 3);
  const int nb = tl & 3, mb = tl >> 2;   // nb in [0,4), mb in [0,256)

  f32x4 acc[8][4];
  #pragma unroll
  for (int i = 0; i < 8; ++i)
    #pragma unroll
    for (int j = 0; j < 4; ++j) acc[i][j] = (f32x4){0.f, 0.f, 0.f, 0.f};

  // per-thread global chunk pointers at slice 0 (advance 4 slices / iter)
  const unsigned short* pA0 = Ap + (((size_t)(2 * mb + 0) * 16384) + tid) * 8;
  const unsigned short* pA1 = Ap + (((size_t)(2 * mb + 1) * 16384) + tid) * 8;
  const unsigned short* pB0 = Bp + (((size_t)(2 * nb + 0) * 16384) + tid) * 8;
  const unsigned short* pB1 = Bp + (((size_t)(2 * nb + 1) * 16384) + tid) * 8;

  // LDS read bases (chunk = u*1024 + h*512 + c*128 + m; c=q in [0,4))
  const unsigned short* rdA = &lA[(wm * 512 + q * 128 + r) * 8];
  const unsigned short* rdB = &lB[((wn >> 1) * 512 + q * 128 + (wn & 1) * 64 + r) * 8];

  bf16x8 af[8], bg[4];

// stage slice (pX + off*4096 shorts) into LDS slot u, operand half h
#define SA(h, off, u) gl_lds16(((h) ? pA1 : pA0) + (size_t)(off) * 4096, \
                               &lA[(((u) * 1024 + (h) * 512 + wave * 64) * 8)])
#define SB(h, off, u) gl_lds16(((h) ? pB1 : pB0) + (size_t)(off) * 4096, \
                               &lB[(((u) * 1024 + (h) * 512 + wave * 64) * 8)])
#define RDS(u) { \
  bg[0] = *(const bf16x8*)&rdB[((u) * 1024 +  0) * 8]; \
  bg[1] = *(const bf16x8*)&rdB[((u) * 1024 + 16) * 8]; \
  bg[2] = *(const bf16x8*)&rdB[((u) * 1024 + 32) * 8]; \
  bg[3] = *(const bf16x8*)&rdB[((u) * 1024 + 48) * 8]; \
  af[0] = *(const bf16x8*)&rdA[((u) * 1024 +   0) * 8]; \
  af[1] = *(const bf16x8*)&rdA[((u) * 1024 +  16) * 8]; \
  af[2] = *(const bf16x8*)&rdA[((u) * 1024 +  32) * 8]; \
  af[3] = *(const bf16x8*)&rdA[((u) * 1024 +  48) * 8]; \
  af[4] = *(const bf16x8*)&rdA[((u) * 1024 +  64) * 8]; \
  af[5] = *(const bf16x8*)&rdA[((u) * 1024 +  80) * 8]; \
  af[6] = *(const bf16x8*)&rdA[((u) * 1024 +  96) * 8]; \
  af[7] = *(const bf16x8*)&rdA[((u) * 1024 + 112) * 8]; }
#define MMA32 \
  asm volatile("s_waitcnt lgkmcnt(0)" ::: "memory"); \
  __builtin_amdgcn_sched_barrier(0); \
  __builtin_amdgcn_s_setprio(1); \
  _Pragma("unroll") \
  for (int mi_ = 0; mi_ < 8; ++mi_) { \
    _Pragma("unroll") \
    for (int ni_ = 0; ni_ < 4; ++ni_) \
      acc[mi_][ni_] = __builtin_amdgcn_mfma_f32_16x16x32_bf16(af[mi_], bg[ni_], acc[mi_][ni_], 0, 0, 0); \
  } \
  __builtin_amdgcn_s_setprio(0);
#define BAR __builtin_amdgcn_s_barrier()
#define VM8 asm volatile("s_waitcnt vmcnt(8)" ::: "memory")
#define VM4 asm volatile("s_waitcnt vmcnt(4)" ::: "memory")
#define VM0 asm volatile("s_waitcnt vmcnt(0)" ::: "memory")

  // ---- prologue: stage slices 0,1,2 into slots 0,1,2 (12 loads) ----
  SA(0, 0, 0); SA(1, 0, 0); SB(0, 0, 0); SB(1, 0, 0);
  SA(0, 1, 1); SA(1, 1, 1); SB(0, 1, 1); SB(1, 1, 1);
  SA(0, 2, 2); SA(1, 2, 2); SB(0, 2, 2); SB(1, 2, 2);
  VM8;  // slice 0 landed (8 newest = slices 1,2)
  BAR;

  // ---- main loop: 7 iters x 4 slices; slice g stages g+3 (depth-3) ----
  #pragma unroll 1
  for (int it2 = 0; it2 < 7; ++it2) {
    RDS(0); SA(0, 3, 3); SA(1, 3, 3); SB(0, 3, 3); SB(1, 3, 3); MMA32; VM8; BAR;
    RDS(1); SA(0, 4, 0); SA(1, 4, 0); SB(0, 4, 0); SB(1, 4, 0); MMA32; VM8; BAR;
    RDS(2); SA(0, 5, 1); SA(1, 5, 1); SB(0, 5, 1); SB(1, 5, 1); MMA32; VM8; BAR;
    RDS(3); SA(0, 6, 2); SA(1, 6, 2); SB(0, 6, 2); SB(1, 6, 2); MMA32; VM8; BAR;
    pA0 += 4 * 4096; pA1 += 4 * 4096; pB0 += 4 * 4096; pB1 += 4 * 4096;
  }

  // ---- tail: slices 28..31 (pointers at slice 28); 28 stages 31 ----
  RDS(0); SA(0, 3, 3); SA(1, 3, 3); SB(0, 3, 3); SB(1, 3, 3); MMA32; VM8; BAR;
  RDS(1); MMA32; VM4; BAR;
  RDS(2); MMA32; VM0; BAR;
  RDS(3); MMA32;

#undef SA
#undef SB
#undef RDS
#undef MMA32
#undef BAR
#undef VM8
#undef VM4
#undef VM0

  // ---- epilogue: tanh(e + addterm) . W_one, partial row sums -> spart ----
  const int nrow = mb >> 2;  // 256-row block lies inside one enc row n
  float addv[4], wv[4];
  #pragma unroll
  for (int ni = 0; ni < 4; ++ni) {
    int col = nb * 256 + wn * 64 + ni * 16 + r;
    addv[ni] = addterm[nrow * 1024 + col];
    wv[ni] = Wone[col];
  }
  #pragma unroll
  for (int mi = 0; mi < 8; ++mi) {
    #pragma unroll
    for (int rr = 0; rr < 4; ++rr) {
      float s = 0.f;
      #pragma unroll
      for (int ni = 0; ni < 4; ++ni)
        s += fast_tanh(acc[mi][ni][rr] + addv[ni]) * wv[ni];
      s += __shfl_xor(s, 1);
      s += __shfl_xor(s, 2);
      s += __shfl_xor(s, 4);
      s += __shfl_xor(s, 8);
      if (r == 0) {
        size_t row = (size_t)mb * 256 + wm * 128 + mi * 16 + q * 4 + rr;
        spart[row * 16 + nb * 4 + wn] = s;
      }
    }
  }
}

// ---- ctx_fused: block (kt, n) recomputes softmax(n) from spart locally,
// then computes ctx[n][kt*64 .. kt*64+63]; kt==0 block writes alpha. ----
__global__ __launch_bounds__(256) void ctx_fused(
    const float* __restrict__ spart, float* __restrict__ alpha,
    const unsigned short* __restrict__ Ap, float* __restrict__ ctx) {
  const int kt = blockIdx.x, n = blockIdx.y, t = threadIdx.x;
  __shared__ float red[8];
  __shared__ float al[1024];

  // softmax over row n (redundant per kt; ~16KB spart row is L2-resident)
  float sv[4];
  #pragma unroll
  for (int i = 0; i < 4; ++i) {
    int l = i * 256 + t;
    const float4* p = (const float4*)(spart + ((size_t)n * 1024 + l) * 16);
    float4 v0 = p[0], v1 = p[1], v2 = p[2], v3 = p[3];
    sv[i] = (v0.x + v0.y + v0.z + v0.w) + (v1.x + v1.y + v1.z + v1.w) +
            (v2.x + v2.y + v2.z + v2.w) + (v3.x + v3.y + v3.z + v3.w);
  }
  float m = fmaxf(fmaxf(sv[0], sv[1]), fmaxf(sv[2], sv[3]));
  for (int o = 32; o > 0; o >>= 1) m = fmaxf(m, __shfl_xor(m, o));
  if ((t & 63) == 0) red[t >> 6] = m;
  __syncthreads();
  float gm = fmaxf(fmaxf(red[0], red[1]), fmaxf(red[2], red[3]));
  float e[4], s = 0.f;
  #pragma unroll
  for (int i = 0; i < 4; ++i) { e[i] = expf(sv[i] - gm); s += e[i]; }
  for (int o = 32; o > 0; o >>= 1) s += __shfl_xor(s, o);
  if ((t & 63) == 0) red[4 + (t >> 6)] = s;
  __syncthreads();
  float inv = 1.0f / (red[4] + red[5] + red[6] + red[7]);
  #pragma unroll
  for (int i = 0; i < 4; ++i) {
    float a = e[i] * inv;
    al[i * 256 + t] = a;
    if (kt == 0) alpha[(size_t)n * 1024 + i * 256 + t] = a;
  }
  __syncthreads();

  // ctx slice: thread group c = t>>5 handles chunk-col c, lanes ls = t&31 slice l
  const int c = t >> 5, ls = t & 31;
  float acc[8] = {0.f, 0.f, 0.f, 0.f, 0.f, 0.f, 0.f, 0.f};
  #pragma unroll 4
  for (int lb = 0; lb < 32; ++lb) {
    int l = lb * 32 + ls;
    int M = n * 1024 + l;
    int T = M >> 7, mm = M & 127;
    us8 v = *(const us8*)(Ap + ((((size_t)T * 16 + kt) * 8 + c) * 128 + mm) * 8);
    float w = al[l];
    #pragma unroll
    for (int j = 0; j < 8; ++j) acc[j] += w * b2f(v[j]);
  }
  #pragma unroll
  for (int off = 1; off <= 16; off <<= 1)
    #pragma unroll
    for (int j = 0; j < 8; ++j) acc[j] += __shfl_xor(acc[j], off);
  if (ls == 0) {
    #pragma unroll
    for (int j = 0; j < 8; ++j) ctx[(size_t)n * 1024 + kt * 64 + c * 8 + j] = acc[j];
  }
}

// ---- h_att[n][j] = ctx[n] . W_att[:,j] + b_att[j] -> d_out[0..65535] ----
// grid (16, 64): block (jb, n) does 64 j's with 4-way k-split.
__global__ __launch_bounds__(256) void hatt_k(
    const float* __restrict__ ctx, const float* __restrict__ W_att,
    const float* __restrict__ b_att, float* __restrict__ out) {
  __shared__ float cs[1024];
  __shared__ float red[4][64];
  const int n = blockIdx.y;
  const int jb = blockIdx.x;            // 0..15
  const int t = threadIdx.x;
  for (int i = t; i < 1024; i += 256) cs[i] = ctx[(size_t)n * 1024 + i];
  __syncthreads();
  const int j = jb * 64 + (t & 63);
  const int ks = t >> 6;                // 0..3, k-range [ks*256, ks*256+256)
  float s = 0.f;
  const float* Wp = W_att + (size_t)(ks * 256) * 1024 + j;
  #pragma unroll 8
  for (int k = 0; k < 256; ++k) s += cs[ks * 256 + k] * Wp[(size_t)k * 1024];
  red[ks][t & 63] = s;
  __syncthreads();
  if (t < 64) {
    out[(size_t)n * 1024 + jb * 64 + t] =
        red[0][t] + red[1][t] + red[2][t] + red[3][t] + b_att[jb * 64 + t];
  }
}

extern "C" void kernel_launch(void* const* d_in, const int* in_sizes, int n_in,
                              void* d_out, int out_size, void* d_ws, size_t ws_size,
                              hipStream_t stream) {
  const float* dec_h = (const float*)d_in[0];
  const float* enc   = (const float*)d_in[1];
  const float* W_dec = (const float*)d_in[2];
  const float* b_dec = (const float*)d_in[3];
  const float* W_enc = (const float*)d_in[4];
  const float* b_enc = (const float*)d_in[5];
  const float* W_one = (const float*)d_in[6];
  // d_in[7] = b_one: softmax shift-invariant -> unused
  const float* W_att = (const float*)d_in[8];
  const float* b_att = (const float*)d_in[9];
  float* out = (float*)d_out;

  char* ws = (char*)d_ws;
  const size_t OFF_A   = 0;                        // 134217728
  const size_t OFF_B   = 134217728;                // 2097152
  const size_t OFF_ADD = OFF_B + 2097152;          // 262144
  const size_t OFF_SP  = OFF_ADD + 262144;         // 4194304
  const size_t OFF_CTX = OFF_SP + 4194304;         // 262144
  const size_t NEED    = OFF_CTX + 262144;
  if (ws_size < NEED) {
    fprintf(stderr, "kernel_launch: ws too small (%zu < %zu)\n", ws_size, NEED);
    return;
  }
  unsigned short* Ap = (unsigned short*)(ws + OFF_A);
  unsigned short* Bp = (unsigned short*)(ws + OFF_B);
  float* addterm = (float*)(ws + OFF_ADD);
  float* spart   = (float*)(ws + OFF_SP);
  float* ctx     = (float*)(ws + OFF_CTX);
  float* alpha   = out + 65536;

  prep_k<<<8320, 256, 0, stream>>>(enc, Ap, W_enc, Bp);
  dterm_k<<<256, 256, 0, stream>>>(dec_h, W_dec, b_dec, b_enc, addterm);
  score_gemm<<<1024, 512, 0, stream>>>(Ap, Bp, addterm, W_one, spart);
  ctx_fused<<<dim3(16, 64), 256, 0, stream>>>(spart, alpha, Ap, ctx);
  hatt_k<<<dim3(16, 64), 256, 0, stream>>>(ctx, W_att, b_att, out);
}

// Round 4
// 624.422 us; speedup vs baseline: 1.0423x; 1.0423x over previous
//
#include <hip/hip_runtime.h>
#include <cstdio>
#include <cstdint>

// Bahdanau attention, N=64, L=1024, H=1024.
//   d = dec_h @ W_dec + b_dec
//   e = enc @ W_enc  (65536x1024x1024 bf16 MFMA GEMM, fused epilogue)
//   scores = tanh(d+e+b_enc) . W_one ; alpha = softmax(scores) (b_one drops)
//   ctx = alpha @ enc ; h_att = ctx @ W_att + b_att
//
// 4 launches: prep (pack_b + dterm + pack_a), score_gemm, ctx_fused, hatt.
//
// Packed layout (16B chunks): chunk index = ((T*16 + kt)*8 + c)*128 + m
//   T = row>>7, m = row&127, kt = col>>6, c = (col&63)>>3.
//
// score_gemm schedule (R3, frozen): 32 K-slices of 32-k. LDS 4 slots x 32KB.
// ONE merged phase per slice:
//   RDS (12 ds_read_b128) ; stage slice g+3 (4 gl_lds)
//   lgkmcnt(0); sched_barrier; setprio(1); 32 MFMA; setprio(0); vmcnt(8); BAR
// Epilogue (R4): cross-wn LDS reduction -> spart[row][4] (nb partials only),
// quartering ctx's softmax re-read traffic.

typedef __bf16 bf16x8 __attribute__((ext_vector_type(8)));
typedef float f32x4 __attribute__((ext_vector_type(4)));
typedef unsigned short us8 __attribute__((ext_vector_type(8)));

static __device__ __forceinline__ unsigned short f2b(float f) {
  union { float f; unsigned u; } v; v.f = f;
  unsigned r = (v.u + 0x7fffu + ((v.u >> 16) & 1u)) >> 16;  // RNE
  return (unsigned short)r;
}
static __device__ __forceinline__ float b2f(unsigned short u) {
  union { unsigned u; float f; } v; v.u = ((unsigned)u) << 16;
  return v.f;
}
static __device__ __forceinline__ void gl_lds16(const void* g, void* l) {
  __builtin_amdgcn_global_load_lds(
      (const __attribute__((address_space(1))) unsigned int*)g,
      (__attribute__((address_space(3))) unsigned int*)l, 16, 0, 0);
}
// branch-free tanh: (u-1)/(u+1), u = 2^(2*log2e*|x|); err ~1e-7
static __device__ __forceinline__ float fast_tanh(float x) {
  float ax = __builtin_fminf(__builtin_fabsf(x), 18.0f);
  float u = __builtin_amdgcn_exp2f(ax * 2.88539008177792681f);
  float t = (u - 1.0f) * __builtin_amdgcn_rcpf(u + 1.0f);
  return __builtin_copysignf(t, x);
}

// ---- prep: blocks [0,128) pack_b, [128,384) dterm, [384, 8576) pack_a ----
// XOR-swizzled LDS tile: chunk (row m, chunk c) -> slot m*8 + (c ^ (m&7)).
__global__ __launch_bounds__(256) void prep_k(
    const float* __restrict__ enc, unsigned short* __restrict__ Ap,
    const float* __restrict__ W_enc, unsigned short* __restrict__ Bp,
    const float* __restrict__ dec_h, const float* __restrict__ W_dec,
    const float* __restrict__ b_dec, const float* __restrict__ b_enc,
    float* __restrict__ addterm) {
  __shared__ __align__(16) unsigned short tile[8192];  // 16 KB
  const int bid = blockIdx.x;
  const int t = threadIdx.x;

  if (bid < 128) {
    // ---- pack_b: W_enc f32 [k][n] -> Bp bf16 tiled (transposed) ----
    const int Tn = bid >> 4, kt = bid & 15;
    #pragma unroll
    for (int it = 0; it < 8; ++it) {
      int idx = it * 256 + t;
      int kk = idx >> 5, n4 = idx & 31;  // 64 k-rows x 32 float4
      const float4 v = *(const float4*)(W_enc + (size_t)(kt * 64 + kk) * 1024 + Tn * 128 + n4 * 4);
      int c = kk >> 3, j = kk & 7;
      #pragma unroll
      for (int x = 0; x < 4; ++x) {
        int mm = n4 * 4 + x;
        float fv = (x == 0) ? v.x : (x == 1) ? v.y : (x == 2) ? v.z : v.w;
        tile[(mm * 8 + (c ^ (mm & 7))) * 8 + j] = f2b(fv);
      }
    }
    __syncthreads();
    #pragma unroll
    for (int it = 0; it < 4; ++it) {
      int p = it * 256 + t;
      int c = p >> 7, m = p & 127;
      us8 v = *(const us8*)&tile[(m * 8 + (c ^ (m & 7))) * 8];
      *(us8*)(Bp + ((size_t)bid * 1024 + p) * 8) = v;
    }
  } else if (bid < 384) {
    // ---- dterm: addterm[n][j] = dec_h[n] . W_dec[:,j] + b_dec[j] + b_enc[j] ----
    const int bid2 = bid - 128;
    const int jb = bid2 & 3, n = bid2 >> 2;
    float* xs = (float*)tile;
    for (int i = t; i < 1024; i += 256) xs[i] = dec_h[n * 1024 + i];
    __syncthreads();
    int j = jb * 256 + t;
    float s = 0.f;
    #pragma unroll 8
    for (int k = 0; k < 1024; ++k) s += xs[k] * W_dec[(size_t)k * 1024 + j];
    addterm[n * 1024 + j] = s + b_dec[j] + b_enc[j];
  } else {
    // ---- pack_a: enc f32 [65536][1024] -> Ap bf16 tiled ----
    const int ba = bid - 384;            // 8192 = T(512) x kt(16)
    const int T = ba >> 4, kt = ba & 15;
    #pragma unroll
    for (int it = 0; it < 8; ++it) {
      int idx = it * 256 + t;
      int m = idx >> 4, c4 = idx & 15;   // 128 rows x 16 float4
      const float4 v = *(const float4*)(enc + (size_t)(T * 128 + m) * 1024 + kt * 64 + c4 * 4);
      ushort4 o;
      o.x = f2b(v.x); o.y = f2b(v.y); o.z = f2b(v.z); o.w = f2b(v.w);
      int c = c4 >> 1, half = c4 & 1;
      *(ushort4*)&tile[(m * 8 + (c ^ (m & 7))) * 8 + half * 4] = o;
    }
    __syncthreads();
    #pragma unroll
    for (int it = 0; it < 4; ++it) {
      int p = it * 256 + t;              // out chunk pos = c*128 + m
      int c = p >> 7, m = p & 127;
      us8 v = *(const us8*)&tile[(m * 8 + (c ^ (m & 7))) * 8];
      *(us8*)(Ap + ((size_t)ba * 1024 + p) * 8) = v;
    }
  }
}

// ---- fused e-GEMM + tanh + dot(W_one): spart[row][4] partial scores ----
// 256x256 tile, 32 K-slices, 8 waves (wm in {0,1}, wn in {0..3}).
// Per wave: 128x64 output = acc[8][4] of 16x16 frags.
__global__ __launch_bounds__(512, 2) void score_gemm(
    const unsigned short* __restrict__ Ap, const unsigned short* __restrict__ Bp,
    const float* __restrict__ addterm, const float* __restrict__ Wone,
    float* __restrict__ spart) {
  __shared__ __align__(16) unsigned short lA[32768];  // 64 KB: 4 slots x 1024 chunks
  __shared__ __align__(16) unsigned short lB[32768];  // 64 KB
  const int tid = threadIdx.x;
  const int lane = tid & 63, wave = tid >> 6;
  const int wm = wave >> 2, wn = wave & 3;
  const int q = lane >> 4, r = lane & 15;

  // XCD-aware remap: 1024 blocks, xcd = flat&7 gets contiguous tile range;
  // nb fastest so the 4 nb-siblings of one A-slab are L2-adjacent.
  const int flat = blockIdx.x;
  const int tl = (flat & 7) * 128 + (flat >> 3);
  const int nb = tl & 3, mb = tl >> 2;   // nb in [0,4), mb in [0,256)

  f32x4 acc[8][4];
  #pragma unroll
  for (int i = 0; i < 8; ++i)
    #pragma unroll
    for (int j = 0; j < 4; ++j) acc[i][j] = (f32x4){0.f, 0.f, 0.f, 0.f};

  // per-thread global chunk pointers at slice 0 (advance 4 slices / iter)
  const unsigned short* pA0 = Ap + (((size_t)(2 * mb + 0) * 16384) + tid) * 8;
  const unsigned short* pA1 = Ap + (((size_t)(2 * mb + 1) * 16384) + tid) * 8;
  const unsigned short* pB0 = Bp + (((size_t)(2 * nb + 0) * 16384) + tid) * 8;
  const unsigned short* pB1 = Bp + (((size_t)(2 * nb + 1) * 16384) + tid) * 8;

  // LDS read bases (chunk = u*1024 + h*512 + c*128 + m; c=q in [0,4))
  const unsigned short* rdA = &lA[(wm * 512 + q * 128 + r) * 8];
  const unsigned short* rdB = &lB[((wn >> 1) * 512 + q * 128 + (wn & 1) * 64 + r) * 8];

  bf16x8 af[8], bg[4];

// stage slice (pX + off*4096 shorts) into LDS slot u, operand half h
#define SA(h, off, u) gl_lds16(((h) ? pA1 : pA0) + (size_t)(off) * 4096, \
                               &lA[(((u) * 1024 + (h) * 512 + wave * 64) * 8)])
#define SB(h, off, u) gl_lds16(((h) ? pB1 : pB0) + (size_t)(off) * 4096, \
                               &lB[(((u) * 1024 + (h) * 512 + wave * 64) * 8)])
#define RDS(u) { \
  bg[0] = *(const bf16x8*)&rdB[((u) * 1024 +  0) * 8]; \
  bg[1] = *(const bf16x8*)&rdB[((u) * 1024 + 16) * 8]; \
  bg[2] = *(const bf16x8*)&rdB[((u) * 1024 + 32) * 8]; \
  bg[3] = *(const bf16x8*)&rdB[((u) * 1024 + 48) * 8]; \
  af[0] = *(const bf16x8*)&rdA[((u) * 1024 +   0) * 8]; \
  af[1] = *(const bf16x8*)&rdA[((u) * 1024 +  16) * 8]; \
  af[2] = *(const bf16x8*)&rdA[((u) * 1024 +  32) * 8]; \
  af[3] = *(const bf16x8*)&rdA[((u) * 1024 +  48) * 8]; \
  af[4] = *(const bf16x8*)&rdA[((u) * 1024 +  64) * 8]; \
  af[5] = *(const bf16x8*)&rdA[((u) * 1024 +  80) * 8]; \
  af[6] = *(const bf16x8*)&rdA[((u) * 1024 +  96) * 8]; \
  af[7] = *(const bf16x8*)&rdA[((u) * 1024 + 112) * 8]; }
#define MMA32 \
  asm volatile("s_waitcnt lgkmcnt(0)" ::: "memory"); \
  __builtin_amdgcn_sched_barrier(0); \
  __builtin_amdgcn_s_setprio(1); \
  _Pragma("unroll") \
  for (int mi_ = 0; mi_ < 8; ++mi_) { \
    _Pragma("unroll") \
    for (int ni_ = 0; ni_ < 4; ++ni_) \
      acc[mi_][ni_] = __builtin_amdgcn_mfma_f32_16x16x32_bf16(af[mi_], bg[ni_], acc[mi_][ni_], 0, 0, 0); \
  } \
  __builtin_amdgcn_s_setprio(0);
#define BAR __builtin_amdgcn_s_barrier()
#define VM8 asm volatile("s_waitcnt vmcnt(8)" ::: "memory")
#define VM4 asm volatile("s_waitcnt vmcnt(4)" ::: "memory")
#define VM0 asm volatile("s_waitcnt vmcnt(0)" ::: "memory")

  // ---- prologue: stage slices 0,1,2 into slots 0,1,2 (12 loads) ----
  SA(0, 0, 0); SA(1, 0, 0); SB(0, 0, 0); SB(1, 0, 0);
  SA(0, 1, 1); SA(1, 1, 1); SB(0, 1, 1); SB(1, 1, 1);
  SA(0, 2, 2); SA(1, 2, 2); SB(0, 2, 2); SB(1, 2, 2);
  VM8;  // slice 0 landed (8 newest = slices 1,2)
  BAR;

  // ---- main loop: 7 iters x 4 slices; slice g stages g+3 (depth-3) ----
  #pragma unroll 1
  for (int it2 = 0; it2 < 7; ++it2) {
    RDS(0); SA(0, 3, 3); SA(1, 3, 3); SB(0, 3, 3); SB(1, 3, 3); MMA32; VM8; BAR;
    RDS(1); SA(0, 4, 0); SA(1, 4, 0); SB(0, 4, 0); SB(1, 4, 0); MMA32; VM8; BAR;
    RDS(2); SA(0, 5, 1); SA(1, 5, 1); SB(0, 5, 1); SB(1, 5, 1); MMA32; VM8; BAR;
    RDS(3); SA(0, 6, 2); SA(1, 6, 2); SB(0, 6, 2); SB(1, 6, 2); MMA32; VM8; BAR;
    pA0 += 4 * 4096; pA1 += 4 * 4096; pB0 += 4 * 4096; pB1 += 4 * 4096;
  }

  // ---- tail: slices 28..31 (pointers at slice 28); 28 stages 31 ----
  RDS(0); SA(0, 3, 3); SA(1, 3, 3); SB(0, 3, 3); SB(1, 3, 3); MMA32; VM8; BAR;
  RDS(1); MMA32; VM4; BAR;
  RDS(2); MMA32; VM0; BAR;
  RDS(3); MMA32;

#undef SA
#undef SB
#undef RDS
#undef MMA32
#undef BAR
#undef VM8
#undef VM4
#undef VM0

  // ---- epilogue: tanh(e + addterm) . W_one, cross-wn reduce -> spart[row][4]
  const int nrow = mb >> 2;  // 256-row block lies inside one enc row n
  float addv[4], wv[4];
  #pragma unroll
  for (int ni = 0; ni < 4; ++ni) {
    int col = nb * 256 + wn * 64 + ni * 16 + r;
    addv[ni] = addterm[nrow * 1024 + col];
    wv[ni] = Wone[col];
  }
  // sred[row_local][wn]: reuse lA bytes [0,4096). Slot-0 readers retired at
  // slice 28 (>=2 barriers ago); all waves are past the slice-30 exit BAR,
  // and their remaining reads hit slot 3 / lB only -> disjoint, safe.
  float* sred = (float*)lA;
  #pragma unroll
  for (int mi = 0; mi < 8; ++mi) {
    #pragma unroll
    for (int rr = 0; rr < 4; ++rr) {
      float s = 0.f;
      #pragma unroll
      for (int ni = 0; ni < 4; ++ni)
        s += fast_tanh(acc[mi][ni][rr] + addv[ni]) * wv[ni];
      s += __shfl_xor(s, 1);
      s += __shfl_xor(s, 2);
      s += __shfl_xor(s, 4);
      s += __shfl_xor(s, 8);
      if (r == 0) sred[(wm * 128 + mi * 16 + q * 4 + rr) * 4 + wn] = s;
    }
  }
  __syncthreads();
  if (tid < 256) {
    float4 v = *(const float4*)&sred[tid * 4];
    spart[((size_t)mb * 256 + tid) * 4 + nb] = v.x + v.y + v.z + v.w;
  }
}

// ---- ctx_fused: block (kt, n) recomputes softmax(n) from spart locally,
// then computes ctx[n][kt*64 .. kt*64+63]; kt==0 block writes alpha. ----
__global__ __launch_bounds__(256) void ctx_fused(
    const float* __restrict__ spart, float* __restrict__ alpha,
    const unsigned short* __restrict__ Ap, float* __restrict__ ctx) {
  const int kt = blockIdx.x, n = blockIdx.y, t = threadIdx.x;
  __shared__ float red[8];
  __shared__ float al[1024];

  // softmax over row n (redundant per kt; 16KB spart row is L2-resident)
  float sv[4];
  #pragma unroll
  for (int i = 0; i < 4; ++i) {
    int l = i * 256 + t;
    float4 v0 = *(const float4*)(spart + ((size_t)n * 1024 + l) * 4);
    sv[i] = (v0.x + v0.y) + (v0.z + v0.w);
  }
  float m = fmaxf(fmaxf(sv[0], sv[1]), fmaxf(sv[2], sv[3]));
  for (int o = 32; o > 0; o >>= 1) m = fmaxf(m, __shfl_xor(m, o));
  if ((t & 63) == 0) red[t >> 6] = m;
  __syncthreads();
  float gm = fmaxf(fmaxf(red[0], red[1]), fmaxf(red[2], red[3]));
  float e[4], s = 0.f;
  #pragma unroll
  for (int i = 0; i < 4; ++i) { e[i] = expf(sv[i] - gm); s += e[i]; }
  for (int o = 32; o > 0; o >>= 1) s += __shfl_xor(s, o);
  if ((t & 63) == 0) red[4 + (t >> 6)] = s;
  __syncthreads();
  float inv = 1.0f / (red[4] + red[5] + red[6] + red[7]);
  #pragma unroll
  for (int i = 0; i < 4; ++i) {
    float a = e[i] * inv;
    al[i * 256 + t] = a;
    if (kt == 0) alpha[(size_t)n * 1024 + i * 256 + t] = a;
  }
  __syncthreads();

  // ctx slice: thread group c = t>>5 handles chunk-col c, lanes ls = t&31 slice l
  const int c = t >> 5, ls = t & 31;
  float acc[8] = {0.f, 0.f, 0.f, 0.f, 0.f, 0.f, 0.f, 0.f};
  #pragma unroll 4
  for (int lb = 0; lb < 32; ++lb) {
    int l = lb * 32 + ls;
    int M = n * 1024 + l;
    int T = M >> 7, mm = M & 127;
    us8 v = *(const us8*)(Ap + ((((size_t)T * 16 + kt) * 8 + c) * 128 + mm) * 8);
    float w = al[l];
    #pragma unroll
    for (int j = 0; j < 8; ++j) acc[j] += w * b2f(v[j]);
  }
  #pragma unroll
  for (int off = 1; off <= 16; off <<= 1)
    #pragma unroll
    for (int j = 0; j < 8; ++j) acc[j] += __shfl_xor(acc[j], off);
  if (ls == 0) {
    #pragma unroll
    for (int j = 0; j < 8; ++j) ctx[(size_t)n * 1024 + kt * 64 + c * 8 + j] = acc[j];
  }
}

// ---- h_att[n][j] = ctx[n] . W_att[:,j] + b_att[j] -> d_out[0..65535] ----
// grid (16, 64): block (jb, n) does 64 j's with 4-way k-split.
__global__ __launch_bounds__(256) void hatt_k(
    const float* __restrict__ ctx, const float* __restrict__ W_att,
    const float* __restrict__ b_att, float* __restrict__ out) {
  __shared__ float cs[1024];
  __shared__ float red[4][64];
  const int n = blockIdx.y;
  const int jb = blockIdx.x;            // 0..15
  const int t = threadIdx.x;
  for (int i = t; i < 1024; i += 256) cs[i] = ctx[(size_t)n * 1024 + i];
  __syncthreads();
  const int j = jb * 64 + (t & 63);
  const int ks = t >> 6;                // 0..3, k-range [ks*256, ks*256+256)
  float s = 0.f;
  const float* Wp = W_att + (size_t)(ks * 256) * 1024 + j;
  #pragma unroll 8
  for (int k = 0; k < 256; ++k) s += cs[ks * 256 + k] * Wp[(size_t)k * 1024];
  red[ks][t & 63] = s;
  __syncthreads();
  if (t < 64) {
    out[(size_t)n * 1024 + jb * 64 + t] =
        red[0][t] + red[1][t] + red[2][t] + red[3][t] + b_att[jb * 64 + t];
  }
}

extern "C" void kernel_launch(void* const* d_in, const int* in_sizes, int n_in,
                              void* d_out, int out_size, void* d_ws, size_t ws_size,
                              hipStream_t stream) {
  const float* dec_h = (const float*)d_in[0];
  const float* enc   = (const float*)d_in[1];
  const float* W_dec = (const float*)d_in[2];
  const float* b_dec = (const float*)d_in[3];
  const float* W_enc = (const float*)d_in[4];
  const float* b_enc = (const float*)d_in[5];
  const float* W_one = (const float*)d_in[6];
  // d_in[7] = b_one: softmax shift-invariant -> unused
  const float* W_att = (const float*)d_in[8];
  const float* b_att = (const float*)d_in[9];
  float* out = (float*)d_out;

  char* ws = (char*)d_ws;
  const size_t OFF_A   = 0;                        // 134217728
  const size_t OFF_B   = 134217728;                // 2097152
  const size_t OFF_ADD = OFF_B + 2097152;          // 262144
  const size_t OFF_SP  = OFF_ADD + 262144;         // 1048576 (spart[row][4])
  const size_t OFF_CTX = OFF_SP + 4194304;         // 262144
  const size_t NEED    = OFF_CTX + 262144;
  if (ws_size < NEED) {
    fprintf(stderr, "kernel_launch: ws too small (%zu < %zu)\n", ws_size, NEED);
    return;
  }
  unsigned short* Ap = (unsigned short*)(ws + OFF_A);
  unsigned short* Bp = (unsigned short*)(ws + OFF_B);
  float* addterm = (float*)(ws + OFF_ADD);
  float* spart   = (float*)(ws + OFF_SP);
  float* ctx     = (float*)(ws + OFF_CTX);
  float* alpha   = out + 65536;

  prep_k<<<8576, 256, 0, stream>>>(enc, Ap, W_enc, Bp, dec_h, W_dec, b_dec, b_enc, addterm);
  score_gemm<<<1024, 512, 0, stream>>>(Ap, Bp, addterm, W_one, spart);
  ctx_fused<<<dim3(16, 64), 256, 0, stream>>>(spart, alpha, Ap, ctx);
  hatt_k<<<dim3(16, 64), 256, 0, stream>>>(ctx, W_att, b_att, out);
}

// Round 6
// 622.326 us; speedup vs baseline: 1.0458x; 1.0034x over previous
//
#include <hip/hip_runtime.h>
#include <cstdio>
#include <cstdint>

// Bahdanau attention, N=64, L=1024, H=1024.
//   d = dec_h @ W_dec + b_dec
//   e = enc @ W_enc  (65536x1024x1024 bf16 MFMA GEMM, fused epilogue)
//   scores = tanh(d+e+b_enc) . W_one ; alpha = softmax(scores) (b_one drops)
//   ctx = alpha @ enc ; h_att = ctx @ W_att + b_att
//
// 4 launches: prep (pack_b + dterm + pack_a), score_gemm, ctx_fused, hatt.
//
// Packed layout (16B chunks): chunk index = ((T*16 + kt)*8 + c)*128 + m
//   T = row>>7, m = row&127, kt = col>>6, c = (col&63)>>3.
//
// R5/R6: f2b is a NATIVE (__bf16) cast (compiler emits v_cvt_pk_bf16_f32,
// 2 elem/op) instead of hand-rolled RNE bit-twiddling (~4-5 VALU ops/elem).
// prep_k was VALU-bound on conversion (~220 us of VALU vs 61 us HBM floor).
// Rounding is still RNE -> results bit-identical.
// (R5 run died on container acquisition, not kernel: resubmitted unchanged.)
//
// score_gemm schedule (R3, frozen): 32 K-slices of 32-k. LDS 4 slots x 32KB.
// ONE merged phase per slice:
//   RDS (12 ds_read_b128) ; stage slice g+3 (4 gl_lds)
//   lgkmcnt(0); sched_barrier; setprio(1); 32 MFMA; setprio(0); vmcnt(8); BAR
// Epilogue: cross-wn LDS reduction -> spart[row][4].

typedef __bf16 bf16x8 __attribute__((ext_vector_type(8)));
typedef float f32x4 __attribute__((ext_vector_type(4)));
typedef unsigned short us8 __attribute__((ext_vector_type(8)));

static __device__ __forceinline__ unsigned short f2b(float f) {
  __bf16 h = (__bf16)f;                       // native cast -> v_cvt_pk_bf16_f32 (RNE)
  return __builtin_bit_cast(unsigned short, h);
}
static __device__ __forceinline__ float b2f(unsigned short u) {
  union { unsigned u; float f; } v; v.u = ((unsigned)u) << 16;
  return v.f;
}
static __device__ __forceinline__ void gl_lds16(const void* g, void* l) {
  __builtin_amdgcn_global_load_lds(
      (const __attribute__((address_space(1))) unsigned int*)g,
      (__attribute__((address_space(3))) unsigned int*)l, 16, 0, 0);
}
// branch-free tanh: (u-1)/(u+1), u = 2^(2*log2e*|x|); err ~1e-7
static __device__ __forceinline__ float fast_tanh(float x) {
  float ax = __builtin_fminf(__builtin_fabsf(x), 18.0f);
  float u = __builtin_amdgcn_exp2f(ax * 2.88539008177792681f);
  float t = (u - 1.0f) * __builtin_amdgcn_rcpf(u + 1.0f);
  return __builtin_copysignf(t, x);
}

// ---- prep: blocks [0,128) pack_b, [128,384) dterm, [384, 8576) pack_a ----
// XOR-swizzled LDS tile: chunk (row m, chunk c) -> slot m*8 + (c ^ (m&7)).
__global__ __launch_bounds__(256) void prep_k(
    const float* __restrict__ enc, unsigned short* __restrict__ Ap,
    const float* __restrict__ W_enc, unsigned short* __restrict__ Bp,
    const float* __restrict__ dec_h, const float* __restrict__ W_dec,
    const float* __restrict__ b_dec, const float* __restrict__ b_enc,
    float* __restrict__ addterm) {
  __shared__ __align__(16) unsigned short tile[8192];  // 16 KB
  const int bid = blockIdx.x;
  const int t = threadIdx.x;

  if (bid < 128) {
    // ---- pack_b: W_enc f32 [k][n] -> Bp bf16 tiled (transposed) ----
    const int Tn = bid >> 4, kt = bid & 15;
    #pragma unroll
    for (int it = 0; it < 8; ++it) {
      int idx = it * 256 + t;
      int kk = idx >> 5, n4 = idx & 31;  // 64 k-rows x 32 float4
      const float4 v = *(const float4*)(W_enc + (size_t)(kt * 64 + kk) * 1024 + Tn * 128 + n4 * 4);
      int c = kk >> 3, j = kk & 7;
      unsigned short s0 = f2b(v.x), s1 = f2b(v.y), s2 = f2b(v.z), s3 = f2b(v.w);
      int mm0 = n4 * 4;
      tile[((mm0 + 0) * 8 + (c ^ ((mm0 + 0) & 7))) * 8 + j] = s0;
      tile[((mm0 + 1) * 8 + (c ^ ((mm0 + 1) & 7))) * 8 + j] = s1;
      tile[((mm0 + 2) * 8 + (c ^ ((mm0 + 2) & 7))) * 8 + j] = s2;
      tile[((mm0 + 3) * 8 + (c ^ ((mm0 + 3) & 7))) * 8 + j] = s3;
    }
    __syncthreads();
    #pragma unroll
    for (int it = 0; it < 4; ++it) {
      int p = it * 256 + t;
      int c = p >> 7, m = p & 127;
      us8 v = *(const us8*)&tile[(m * 8 + (c ^ (m & 7))) * 8];
      *(us8*)(Bp + ((size_t)bid * 1024 + p) * 8) = v;
    }
  } else if (bid < 384) {
    // ---- dterm: addterm[n][j] = dec_h[n] . W_dec[:,j] + b_dec[j] + b_enc[j] ----
    const int bid2 = bid - 128;
    const int jb = bid2 & 3, n = bid2 >> 2;
    float* xs = (float*)tile;
    for (int i = t; i < 1024; i += 256) xs[i] = dec_h[n * 1024 + i];
    __syncthreads();
    int j = jb * 256 + t;
    float s = 0.f;
    #pragma unroll 8
    for (int k = 0; k < 1024; ++k) s += xs[k] * W_dec[(size_t)k * 1024 + j];
    addterm[n * 1024 + j] = s + b_dec[j] + b_enc[j];
  } else {
    // ---- pack_a: enc f32 [65536][1024] -> Ap bf16 tiled ----
    const int ba = bid - 384;            // 8192 = T(512) x kt(16)
    const int T = ba >> 4, kt = ba & 15;
    #pragma unroll
    for (int it = 0; it < 8; ++it) {
      int idx = it * 256 + t;
      int m = idx >> 4, c4 = idx & 15;   // 128 rows x 16 float4
      const float4 v = *(const float4*)(enc + (size_t)(T * 128 + m) * 1024 + kt * 64 + c4 * 4);
      ushort4 o;
      o.x = f2b(v.x); o.y = f2b(v.y); o.z = f2b(v.z); o.w = f2b(v.w);
      int c = c4 >> 1, half = c4 & 1;
      *(ushort4*)&tile[(m * 8 + (c ^ (m & 7))) * 8 + half * 4] = o;
    }
    __syncthreads();
    #pragma unroll
    for (int it = 0; it < 4; ++it) {
      int p = it * 256 + t;              // out chunk pos = c*128 + m
      int c = p >> 7, m = p & 127;
      us8 v = *(const us8*)&tile[(m * 8 + (c ^ (m & 7))) * 8];
      *(us8*)(Ap + ((size_t)ba * 1024 + p) * 8) = v;
    }
  }
}

// ---- fused e-GEMM + tanh + dot(W_one): spart[row][4] partial scores ----
// 256x256 tile, 32 K-slices, 8 waves (wm in {0,1}, wn in {0..3}).
// Per wave: 128x64 output = acc[8][4] of 16x16 frags.
__global__ __launch_bounds__(512, 2) void score_gemm(
    const unsigned short* __restrict__ Ap, const unsigned short* __restrict__ Bp,
    const float* __restrict__ addterm, const float* __restrict__ Wone,
    float* __restrict__ spart) {
  __shared__ __align__(16) unsigned short lA[32768];  // 64 KB: 4 slots x 1024 chunks
  __shared__ __align__(16) unsigned short lB[32768];  // 64 KB
  const int tid = threadIdx.x;
  const int lane = tid & 63, wave = tid >> 6;
  const int wm = wave >> 2, wn = wave & 3;
  const int q = lane >> 4, r = lane & 15;

  // XCD-aware remap: 1024 blocks, xcd = flat&7 gets contiguous tile range;
  // nb fastest so the 4 nb-siblings of one A-slab are L2-adjacent.
  const int flat = blockIdx.x;
  const int tl = (flat & 7) * 128 + (flat >> 3);
  const int nb = tl & 3, mb = tl >> 2;   // nb in [0,4), mb in [0,256)

  f32x4 acc[8][4];
  #pragma unroll
  for (int i = 0; i < 8; ++i)
    #pragma unroll
    for (int j = 0; j < 4; ++j) acc[i][j] = (f32x4){0.f, 0.f, 0.f, 0.f};

  // per-thread global chunk pointers at slice 0 (advance 4 slices / iter)
  const unsigned short* pA0 = Ap + (((size_t)(2 * mb + 0) * 16384) + tid) * 8;
  const unsigned short* pA1 = Ap + (((size_t)(2 * mb + 1) * 16384) + tid) * 8;
  const unsigned short* pB0 = Bp + (((size_t)(2 * nb + 0) * 16384) + tid) * 8;
  const unsigned short* pB1 = Bp + (((size_t)(2 * nb + 1) * 16384) + tid) * 8;

  // LDS read bases (chunk = u*1024 + h*512 + c*128 + m; c=q in [0,4))
  const unsigned short* rdA = &lA[(wm * 512 + q * 128 + r) * 8];
  const unsigned short* rdB = &lB[((wn >> 1) * 512 + q * 128 + (wn & 1) * 64 + r) * 8];

  bf16x8 af[8], bg[4];

// stage slice (pX + off*4096 shorts) into LDS slot u, operand half h
#define SA(h, off, u) gl_lds16(((h) ? pA1 : pA0) + (size_t)(off) * 4096, \
                               &lA[(((u) * 1024 + (h) * 512 + wave * 64) * 8)])
#define SB(h, off, u) gl_lds16(((h) ? pB1 : pB0) + (size_t)(off) * 4096, \
                               &lB[(((u) * 1024 + (h) * 512 + wave * 64) * 8)])
#define RDS(u) { \
  bg[0] = *(const bf16x8*)&rdB[((u) * 1024 +  0) * 8]; \
  bg[1] = *(const bf16x8*)&rdB[((u) * 1024 + 16) * 8]; \
  bg[2] = *(const bf16x8*)&rdB[((u) * 1024 + 32) * 8]; \
  bg[3] = *(const bf16x8*)&rdB[((u) * 1024 + 48) * 8]; \
  af[0] = *(const bf16x8*)&rdA[((u) * 1024 +   0) * 8]; \
  af[1] = *(const bf16x8*)&rdA[((u) * 1024 +  16) * 8]; \
  af[2] = *(const bf16x8*)&rdA[((u) * 1024 +  32) * 8]; \
  af[3] = *(const bf16x8*)&rdA[((u) * 1024 +  48) * 8]; \
  af[4] = *(const bf16x8*)&rdA[((u) * 1024 +  64) * 8]; \
  af[5] = *(const bf16x8*)&rdA[((u) * 1024 +  80) * 8]; \
  af[6] = *(const bf16x8*)&rdA[((u) * 1024 +  96) * 8]; \
  af[7] = *(const bf16x8*)&rdA[((u) * 1024 + 112) * 8]; }
#define MMA32 \
  asm volatile("s_waitcnt lgkmcnt(0)" ::: "memory"); \
  __builtin_amdgcn_sched_barrier(0); \
  __builtin_amdgcn_s_setprio(1); \
  _Pragma("unroll") \
  for (int mi_ = 0; mi_ < 8; ++mi_) { \
    _Pragma("unroll") \
    for (int ni_ = 0; ni_ < 4; ++ni_) \
      acc[mi_][ni_] = __builtin_amdgcn_mfma_f32_16x16x32_bf16(af[mi_], bg[ni_], acc[mi_][ni_], 0, 0, 0); \
  } \
  __builtin_amdgcn_s_setprio(0);
#define BAR __builtin_amdgcn_s_barrier()
#define VM8 asm volatile("s_waitcnt vmcnt(8)" ::: "memory")
#define VM4 asm volatile("s_waitcnt vmcnt(4)" ::: "memory")
#define VM0 asm volatile("s_waitcnt vmcnt(0)" ::: "memory")

  // ---- prologue: stage slices 0,1,2 into slots 0,1,2 (12 loads) ----
  SA(0, 0, 0); SA(1, 0, 0); SB(0, 0, 0); SB(1, 0, 0);
  SA(0, 1, 1); SA(1, 1, 1); SB(0, 1, 1); SB(1, 1, 1);
  SA(0, 2, 2); SA(1, 2, 2); SB(0, 2, 2); SB(1, 2, 2);
  VM8;  // slice 0 landed (8 newest = slices 1,2)
  BAR;

  // ---- main loop: 7 iters x 4 slices; slice g stages g+3 (depth-3) ----
  #pragma unroll 1
  for (int it2 = 0; it2 < 7; ++it2) {
    RDS(0); SA(0, 3, 3); SA(1, 3, 3); SB(0, 3, 3); SB(1, 3, 3); MMA32; VM8; BAR;
    RDS(1); SA(0, 4, 0); SA(1, 4, 0); SB(0, 4, 0); SB(1, 4, 0); MMA32; VM8; BAR;
    RDS(2); SA(0, 5, 1); SA(1, 5, 1); SB(0, 5, 1); SB(1, 5, 1); MMA32; VM8; BAR;
    RDS(3); SA(0, 6, 2); SA(1, 6, 2); SB(0, 6, 2); SB(1, 6, 2); MMA32; VM8; BAR;
    pA0 += 4 * 4096; pA1 += 4 * 4096; pB0 += 4 * 4096; pB1 += 4 * 4096;
  }

  // ---- tail: slices 28..31 (pointers at slice 28); 28 stages 31 ----
  RDS(0); SA(0, 3, 3); SA(1, 3, 3); SB(0, 3, 3); SB(1, 3, 3); MMA32; VM8; BAR;
  RDS(1); MMA32; VM4; BAR;
  RDS(2); MMA32; VM0; BAR;
  RDS(3); MMA32;

#undef SA
#undef SB
#undef RDS
#undef MMA32
#undef BAR
#undef VM8
#undef VM4
#undef VM0

  // ---- epilogue: tanh(e + addterm) . W_one, cross-wn reduce -> spart[row][4]
  const int nrow = mb >> 2;  // 256-row block lies inside one enc row n
  float addv[4], wv[4];
  #pragma unroll
  for (int ni = 0; ni < 4; ++ni) {
    int col = nb * 256 + wn * 64 + ni * 16 + r;
    addv[ni] = addterm[nrow * 1024 + col];
    wv[ni] = Wone[col];
  }
  // sred[row_local][wn]: reuse lA bytes [0,4096). Slot-0 readers retired at
  // slice 28 (>=2 barriers ago); all waves are past the slice-30 exit BAR,
  // and their remaining reads hit slot 3 / lB only -> disjoint, safe.
  float* sred = (float*)lA;
  #pragma unroll
  for (int mi = 0; mi < 8; ++mi) {
    #pragma unroll
    for (int rr = 0; rr < 4; ++rr) {
      float s = 0.f;
      #pragma unroll
      for (int ni = 0; ni < 4; ++ni)
        s += fast_tanh(acc[mi][ni][rr] + addv[ni]) * wv[ni];
      s += __shfl_xor(s, 1);
      s += __shfl_xor(s, 2);
      s += __shfl_xor(s, 4);
      s += __shfl_xor(s, 8);
      if (r == 0) sred[(wm * 128 + mi * 16 + q * 4 + rr) * 4 + wn] = s;
    }
  }
  __syncthreads();
  if (tid < 256) {
    float4 v = *(const float4*)&sred[tid * 4];
    spart[((size_t)mb * 256 + tid) * 4 + nb] = v.x + v.y + v.z + v.w;
  }
}

// ---- ctx_fused: block (kt, n) recomputes softmax(n) from spart locally,
// then computes ctx[n][kt*64 .. kt*64+63]; kt==0 block writes alpha. ----
__global__ __launch_bounds__(256) void ctx_fused(
    const float* __restrict__ spart, float* __restrict__ alpha,
    const unsigned short* __restrict__ Ap, float* __restrict__ ctx) {
  const int kt = blockIdx.x, n = blockIdx.y, t = threadIdx.x;
  __shared__ float red[8];
  __shared__ float al[1024];

  // softmax over row n (redundant per kt; 16KB spart row is L2-resident)
  float sv[4];
  #pragma unroll
  for (int i = 0; i < 4; ++i) {
    int l = i * 256 + t;
    float4 v0 = *(const float4*)(spart + ((size_t)n * 1024 + l) * 4);
    sv[i] = (v0.x + v0.y) + (v0.z + v0.w);
  }
  float m = fmaxf(fmaxf(sv[0], sv[1]), fmaxf(sv[2], sv[3]));
  for (int o = 32; o > 0; o >>= 1) m = fmaxf(m, __shfl_xor(m, o));
  if ((t & 63) == 0) red[t >> 6] = m;
  __syncthreads();
  float gm = fmaxf(fmaxf(red[0], red[1]), fmaxf(red[2], red[3]));
  float e[4], s = 0.f;
  #pragma unroll
  for (int i = 0; i < 4; ++i) { e[i] = expf(sv[i] - gm); s += e[i]; }
  for (int o = 32; o > 0; o >>= 1) s += __shfl_xor(s, o);
  if ((t & 63) == 0) red[4 + (t >> 6)] = s;
  __syncthreads();
  float inv = 1.0f / (red[4] + red[5] + red[6] + red[7]);
  #pragma unroll
  for (int i = 0; i < 4; ++i) {
    float a = e[i] * inv;
    al[i * 256 + t] = a;
    if (kt == 0) alpha[(size_t)n * 1024 + i * 256 + t] = a;
  }
  __syncthreads();

  // ctx slice: thread group c = t>>5 handles chunk-col c, lanes ls = t&31 slice l
  const int c = t >> 5, ls = t & 31;
  float acc[8] = {0.f, 0.f, 0.f, 0.f, 0.f, 0.f, 0.f, 0.f};
  #pragma unroll 4
  for (int lb = 0; lb < 32; ++lb) {
    int l = lb * 32 + ls;
    int M = n * 1024 + l;
    int T = M >> 7, mm = M & 127;
    us8 v = *(const us8*)(Ap + ((((size_t)T * 16 + kt) * 8 + c) * 128 + mm) * 8);
    float w = al[l];
    #pragma unroll
    for (int j = 0; j < 8; ++j) acc[j] += w * b2f(v[j]);
  }
  #pragma unroll
  for (int off = 1; off <= 16; off <<= 1)
    #pragma unroll
    for (int j = 0; j < 8; ++j) acc[j] += __shfl_xor(acc[j], off);
  if (ls == 0) {
    #pragma unroll
    for (int j = 0; j < 8; ++j) ctx[(size_t)n * 1024 + kt * 64 + c * 8 + j] = acc[j];
  }
}

// ---- h_att[n][j] = ctx[n] . W_att[:,j] + b_att[j] -> d_out[0..65535] ----
// grid (16, 64): block (jb, n) does 64 j's with 4-way k-split.
__global__ __launch_bounds__(256) void hatt_k(
    const float* __restrict__ ctx, const float* __restrict__ W_att,
    const float* __restrict__ b_att, float* __restrict__ out) {
  __shared__ float cs[1024];
  __shared__ float red[4][64];
  const int n = blockIdx.y;
  const int jb = blockIdx.x;            // 0..15
  const int t = threadIdx.x;
  for (int i = t; i < 1024; i += 256) cs[i] = ctx[(size_t)n * 1024 + i];
  __syncthreads();
  const int j = jb * 64 + (t & 63);
  const int ks = t >> 6;                // 0..3, k-range [ks*256, ks*256+256)
  float s = 0.f;
  const float* Wp = W_att + (size_t)(ks * 256) * 1024 + j;
  #pragma unroll 8
  for (int k = 0; k < 256; ++k) s += cs[ks * 256 + k] * Wp[(size_t)k * 1024];
  red[ks][t & 63] = s;
  __syncthreads();
  if (t < 64) {
    out[(size_t)n * 1024 + jb * 64 + t] =
        red[0][t] + red[1][t] + red[2][t] + red[3][t] + b_att[jb * 64 + t];
  }
}

extern "C" void kernel_launch(void* const* d_in, const int* in_sizes, int n_in,
                              void* d_out, int out_size, void* d_ws, size_t ws_size,
                              hipStream_t stream) {
  const float* dec_h = (const float*)d_in[0];
  const float* enc   = (const float*)d_in[1];
  const float* W_dec = (const float*)d_in[2];
  const float* b_dec = (const float*)d_in[3];
  const float* W_enc = (const float*)d_in[4];
  const float* b_enc = (const float*)d_in[5];
  const float* W_one = (const float*)d_in[6];
  // d_in[7] = b_one: softmax shift-invariant -> unused
  const float* W_att = (const float*)d_in[8];
  const float* b_att = (const float*)d_in[9];
  float* out = (float*)d_out;

  char* ws = (char*)d_ws;
  const size_t OFF_A   = 0;                        // 134217728
  const size_t OFF_B   = 134217728;                // 2097152
  const size_t OFF_ADD = OFF_B + 2097152;          // 262144
  const size_t OFF_SP  = OFF_ADD + 262144;         // 1048576 (spart[row][4])
  const size_t OFF_CTX = OFF_SP + 4194304;         // 262144
  const size_t NEED    = OFF_CTX + 262144;
  if (ws_size < NEED) {
    fprintf(stderr, "kernel_launch: ws too small (%zu < %zu)\n", ws_size, NEED);
    return;
  }
  unsigned short* Ap = (unsigned short*)(ws + OFF_A);
  unsigned short* Bp = (unsigned short*)(ws + OFF_B);
  float* addterm = (float*)(ws + OFF_ADD);
  float* spart   = (float*)(ws + OFF_SP);
  float* ctx     = (float*)(ws + OFF_CTX);
  float* alpha   = out + 65536;

  prep_k<<<8576, 256, 0, stream>>>(enc, Ap, W_enc, Bp, dec_h, W_dec, b_dec, b_enc, addterm);
  score_gemm<<<1024, 512, 0, stream>>>(Ap, Bp, addterm, W_one, spart);
  ctx_fused<<<dim3(16, 64), 256, 0, stream>>>(spart, alpha, Ap, ctx);
  hatt_k<<<dim3(16, 64), 256, 0, stream>>>(ctx, W_att, b_att, out);
}